// Round 1
// baseline (2909.292 us; speedup 1.0000x reference)
//
#include <hip/hip_runtime.h>
#include <math.h>

// CodeWiseAttention: m[b,n,:] = softmax_l(lf[n,:] . x[b,l,:]) @ x[b]
// B=8 L=2500 E=100 N=8922, fp32 in/out.
constexpr int Bb = 8;
constexpr int Ll = 2500;
constexpr int Ee = 100;
constexpr int Nn = 8922;
constexpr int NT = 16;    // n's per block (4 per wave, 4 waves)
constexpr int LT = 64;    // l-tile (one l per lane)
constexpr int LTP = 65;   // padded lane-dim stride (odd -> conflict-free both axes)

__global__ __launch_bounds__(256)
void cwa_fwd(const float* __restrict__ x, const float* __restrict__ lf,
             float* __restrict__ out) {
    __shared__ float q[NT][Ee];        // label_feature tile (reads are wave-broadcast)
    __shared__ float xt[Ee][LTP];      // x tile TRANSPOSED: xt[e][l_local]
    __shared__ float pl[NT][LT];       // per-tile probabilities

    const int tid  = threadIdx.x;
    const int lane = tid & 63;
    const int w    = tid >> 6;         // wave id 0..3, owns n_local 4w..4w+3
    const int b    = blockIdx.y;
    const int n0   = blockIdx.x * NT;

    // stage q (label_feature rows n0..n0+15); zero-pad past N
    for (int idx = tid; idx < NT * Ee; idx += 256) {
        int nl = idx / Ee, e = idx - nl * Ee;
        int n = n0 + nl;
        q[nl][e] = (n < Nn) ? lf[n * Ee + e] : 0.0f;
    }

    float m_i[4], s_i[4], a0[4], a1[4];
#pragma unroll
    for (int i = 0; i < 4; i++) { m_i[i] = -INFINITY; s_i[i] = 0.f; a0[i] = 0.f; a1[i] = 0.f; }

    const float* xb = x + (size_t)b * Ll * Ee;
    const bool hi_ok = lane < (Ee - 64);   // lane < 36 handles e = 64+lane

    for (int l0 = 0; l0 < Ll; l0 += LT) {
        const int nrows = min(LT, Ll - l0);     // last tile: 4
        __syncthreads();   // previous tile's xt/pl readers done before overwrite
        // stage x[l0 .. l0+nrows) transposed; zero the tail rows
        for (int idx = tid; idx < LT * (Ee / 4); idx += 256) {
            int r  = idx / (Ee / 4);            // l_local
            int c4 = idx - r * (Ee / 4);        // float4 column
            float4 v = make_float4(0.f, 0.f, 0.f, 0.f);
            if (r < nrows)
                v = *reinterpret_cast<const float4*>(xb + (size_t)(l0 + r) * Ee + c4 * 4);
            xt[c4 * 4 + 0][r] = v.x;
            xt[c4 * 4 + 1][r] = v.y;
            xt[c4 * 4 + 2][r] = v.z;
            xt[c4 * 4 + 3][r] = v.w;
        }
        __syncthreads();

        // scores: lane computes l_local = lane for its wave's 4 n's
        float sc[4] = {0.f, 0.f, 0.f, 0.f};
        for (int e = 0; e < Ee; e++) {
            float xv = xt[e][lane];             // conflict-free (stride 65)
#pragma unroll
            for (int i = 0; i < 4; i++) sc[i] = fmaf(q[4 * w + i][e], xv, sc[i]);
        }
        const bool valid = lane < nrows;
#pragma unroll
        for (int i = 0; i < 4; i++) {
            float s = valid ? sc[i] : -INFINITY;
            float tm = s;
#pragma unroll
            for (int msk = 32; msk >= 1; msk >>= 1) tm = fmaxf(tm, __shfl_xor(tm, msk, 64));
            float mn = fmaxf(m_i[i], tm);
            float p  = __expf(s - mn);          // -inf -> 0 (masked tail lanes)
            float sm = p;
#pragma unroll
            for (int msk = 32; msk >= 1; msk >>= 1) sm += __shfl_xor(sm, msk, 64);
            float scale = __expf(m_i[i] - mn);  // first tile: exp(-inf)=0
            s_i[i] = s_i[i] * scale + sm;
            m_i[i] = mn;
            a0[i] *= scale; a1[i] *= scale;
            pl[4 * w + i][lane] = p;
        }
        __syncthreads();

        // PV: lane owns e = lane (and e = 64+lane if < 100)
#pragma unroll 4
        for (int l = 0; l < LT; l++) {
            float xv0 = xt[lane][l];            // consecutive lanes -> consecutive rows, free
            float xv1 = hi_ok ? xt[64 + lane][l] : 0.f;
#pragma unroll
            for (int i = 0; i < 4; i++) {
                float pv = pl[4 * w + i][l];    // wave-broadcast
                a0[i] = fmaf(pv, xv0, a0[i]);
                a1[i] = fmaf(pv, xv1, a1[i]);
            }
        }
    }

    // epilogue: out[b,n,e] = acc[e]/s
#pragma unroll
    for (int i = 0; i < 4; i++) {
        int n = n0 + 4 * w + i;
        if (n >= Nn) continue;
        float inv = 1.0f / s_i[i];
        size_t base = ((size_t)b * Nn + n) * Ee;
        out[base + lane] = a0[i] * inv;
        if (hi_ok) out[base + 64 + lane] = a1[i] * inv;
    }
}

extern "C" void kernel_launch(void* const* d_in, const int* in_sizes, int n_in,
                              void* d_out, int out_size, void* d_ws, size_t ws_size,
                              hipStream_t stream) {
    const float* x  = (const float*)d_in[0];   // [8, 2500, 100]
    const float* lf = (const float*)d_in[1];   // [8922, 100]
    float* out = (float*)d_out;                // [8, 8922, 100]
    dim3 grid((Nn + NT - 1) / NT, Bb);
    cwa_fwd<<<grid, dim3(256), 0, stream>>>(x, lf, out);
}

// Round 2
// 270.175 us; speedup vs baseline: 10.7682x; 10.7682x over previous
//
#include <hip/hip_runtime.h>
#include <math.h>
#include <stdint.h>

typedef __attribute__((ext_vector_type(8))) _Float16 half8;
typedef __attribute__((ext_vector_type(4))) _Float16 half4;
typedef __attribute__((ext_vector_type(4))) float f32x4;

constexpr int Bb = 8, Ll = 2500, Ee = 100, Nn = 8922;
constexpr int LP = 2560, EP = 128, NP = 8960;   // padded dims
constexpr int LT = 64;                          // l-tile
constexpr int NTILES = LP / LT;                 // 40
constexpr int NTB = 128;                        // n per block (8 waves x 16)

constexpr size_t SZ_LF = (size_t)NP * EP * 2;
constexpr size_t SZ_XW = (size_t)Bb * LP * EP * 2;
constexpr size_t OFF_XW = SZ_LF;
constexpr size_t OFF_XT = OFF_XW + SZ_XW;
constexpr size_t WS_NEED = OFF_XT + SZ_XW;      // ~12.2 MB

__device__ __forceinline__ void gload16(const void* g, void* l) {
    __builtin_amdgcn_global_load_lds(
        (const __attribute__((address_space(1))) uint32_t*)g,
        (__attribute__((address_space(3))) uint32_t*)l, 16, 0, 0);
}

// ---------- prepass: lf -> f16 [NP][EP], bias col e=127 = 1.0, no swizzle ----------
__global__ __launch_bounds__(256)
void prep_lf(const float* __restrict__ lf, uint32_t* __restrict__ dst) {
    int idx = blockIdx.x * 256 + threadIdx.x;   // n*64 + ep
    int n = idx >> 6, ep = idx & 63;
    int e0 = 2 * ep, e1 = e0 + 1;
    float f0 = (n < Nn && e0 < Ee) ? lf[(size_t)n * Ee + e0] : 0.f;
    float f1 = (n < Nn && e1 < Ee) ? lf[(size_t)n * Ee + e1] : (e1 == 127 ? 1.0f : 0.f);
    union { _Float16 h[2]; uint32_t u; } cv;
    cv.h[0] = (_Float16)f0; cv.h[1] = (_Float16)f1;
    dst[idx] = cv.u;
}

// ---------- prepass: x -> f16 [B][LP][EP], row-swizzled; x[l>=Ll][127] = -20000 ----------
__global__ __launch_bounds__(256)
void prep_xw(const float* __restrict__ x, uint32_t* __restrict__ dst) {
    int idx = blockIdx.x * 256 + threadIdx.x;   // row*64 + ep
    int row = idx >> 6, ep = idx & 63;
    int b = row / LP, l = row - b * LP;
    int e0 = 2 * ep, e1 = e0 + 1;
    const size_t src = ((size_t)b * Ll + l) * Ee;
    float f0 = (l < Ll && e0 < Ee) ? x[src + e0] : 0.f;
    float f1;
    if (e1 < Ee)       f1 = (l < Ll) ? x[src + e1] : 0.f;
    else if (e1 == 127) f1 = (l < Ll) ? 0.f : -20000.f;   // softmax mask bias
    else               f1 = 0.f;
    union { _Float16 h[2]; uint32_t u; } cv;
    cv.h[0] = (_Float16)f0; cv.h[1] = (_Float16)f1;
    int boff = (4 * ep) ^ ((l & 7) << 4);       // swizzle 16B blocks within 128B row-half
    dst[(size_t)row * 64 + (boff >> 2)] = cv.u;
}

// ---------- prepass: x^T -> f16 [B][EP][LP], row-swizzled ----------
__global__ __launch_bounds__(256)
void prep_xt(const float* __restrict__ x, uint16_t* __restrict__ dst) {
    __shared__ float lx[LT][101];               // +1 pad: 2-way banks on column reads
    int l0 = blockIdx.x * LT;
    int b  = blockIdx.y;
    for (int i = threadIdx.x; i < LT * Ee; i += 256) {
        int ll = i / Ee, e = i - ll * Ee;
        int l = l0 + ll;
        lx[ll][e] = (l < Ll) ? x[((size_t)b * Ll + l) * Ee + e] : 0.f;
    }
    __syncthreads();
    for (int i = threadIdx.x; i < EP * LT; i += 256) {
        int e = i >> 6, ll = i & 63;
        float v = (e < Ee) ? lx[ll][e] : 0.f;
        uint32_t boff = (uint32_t)((2 * ll) ^ ((e & 7) << 4));
        union { _Float16 h; uint16_t u; } cv; cv.h = (_Float16)v;
        dst[((size_t)b * EP + e) * LP + l0 + (boff >> 1)] = cv.u;
    }
}

// ---------- main: flash-style MFMA attention ----------
__global__ __launch_bounds__(512)
void cwa_mfma(const uint16_t* __restrict__ lf16, const uint16_t* __restrict__ xw,
              const uint16_t* __restrict__ xt, float* __restrict__ out) {
    __shared__ __align__(128) char smem[2 * 32768 + 8 * 2048];   // 80 KB
    const int tid = threadIdx.x, lane = tid & 63, w = tid >> 6;
    const int g = lane >> 4, nl = lane & 15;
    const int b = blockIdx.y;
    const int n_base = blockIdx.x * NTB + w * 16;

    // Q fragments (B-operand): lane = col n = nl, k = e = 32ks + 8g + j
    half8 qf[4];
    {
        const uint16_t* qr = lf16 + (size_t)(n_base + nl) * EP + 8 * g;
#pragma unroll
        for (int ks = 0; ks < 4; ks++) qf[ks] = *(const half8*)(qr + 32 * ks);
    }

    f32x4 oacc[7];
#pragma unroll
    for (int es = 0; es < 7; es++) oacc[es] = f32x4{0.f, 0.f, 0.f, 0.f};
    float m_i = -INFINITY, s_i = 0.f;

    const char* xwb = (const char*)(xw + (size_t)b * LP * EP);
    const char* xtb = (const char*)(xt + (size_t)b * EP * LP);

    // stage tile 0 into buf 0
    {
        char* kb = smem; char* vb = smem + 16384;
#pragma unroll
        for (int i = 0; i < 2; i++) {
            int uo = i * 8192 + w * 1024;
            gload16(xwb + uo + lane * 16, kb + uo);
        }
#pragma unroll
        for (int i = 0; i < 2; i++) {
            int e0 = w * 16 + i * 8;
            gload16(xtb + (size_t)(e0 + (lane >> 3)) * (LP * 2) + (lane & 7) * 16,
                    vb + e0 * 128);
        }
    }
    asm volatile("s_waitcnt vmcnt(0)" ::: "memory");
    __syncthreads();

    char* pb = smem + 65536 + w * 2048;     // wave-private P buffer
    const int swp = (nl & 7) << 4;

    for (int t = 0; t < NTILES; t++) {
        const int buf = t & 1;
        const char* kb = smem + buf * 32768;
        const char* vb = kb + 16384;

        // prefetch next tile into other buffer (counted drain at tile end)
        if (t + 1 < NTILES) {
            char* kb2 = smem + (buf ^ 1) * 32768; char* vb2 = kb2 + 16384;
            const char* kg = xwb + (size_t)(t + 1) * LT * EP * 2;
            const char* vg = xtb + (size_t)(t + 1) * LT * 2;
#pragma unroll
            for (int i = 0; i < 2; i++) {
                int uo = i * 8192 + w * 1024;
                gload16(kg + uo + lane * 16, kb2 + uo);
            }
#pragma unroll
            for (int i = 0; i < 2; i++) {
                int e0 = w * 16 + i * 8;
                gload16(vg + (size_t)(e0 + (lane >> 3)) * (LP * 2) + (lane & 7) * 16,
                        vb2 + e0 * 128);
            }
        }

        // ---- QK^T: S^T[l][n] = mfma(A=K, B=Q) ----
        f32x4 sacc[4];
#pragma unroll
        for (int ls = 0; ls < 4; ls++) sacc[ls] = f32x4{0.f, 0.f, 0.f, 0.f};
#pragma unroll
        for (int ls = 0; ls < 4; ls++) {
            const int lrow = 16 * ls + nl;
            const char* kr = kb + lrow * 256;
            const int sw = (lrow & 7) << 4;
#pragma unroll
            for (int ks = 0; ks < 4; ks++) {
                half8 kf = *(const half8*)(kr + ((64 * ks + 16 * g) ^ sw));
                sacc[ls] = __builtin_amdgcn_mfma_f32_16x16x32_f16(kf, qf[ks], sacc[ls], 0, 0, 0);
            }
        }

        // ---- online softmax over l (lane's 16 values all share col n = nl) ----
        float tm = -INFINITY;
#pragma unroll
        for (int ls = 0; ls < 4; ls++)
#pragma unroll
            for (int r = 0; r < 4; r++) tm = fmaxf(tm, sacc[ls][r]);
        tm = fmaxf(tm, __shfl_xor(tm, 16, 64));
        tm = fmaxf(tm, __shfl_xor(tm, 32, 64));
        const float mn = fmaxf(m_i, tm);
        const float scale = __expf(m_i - mn);
        float ts = 0.f;
        half4 ph[4];
#pragma unroll
        for (int ls = 0; ls < 4; ls++)
#pragma unroll
            for (int r = 0; r < 4; r++) {
                float pv = __expf(sacc[ls][r] - mn);
                ts += pv;
                ph[ls][r] = (_Float16)pv;
            }
        ts += __shfl_xor(ts, 16, 64);
        ts += __shfl_xor(ts, 32, 64);
        s_i = s_i * scale + ts;
        m_i = mn;

        // rescale output acc (row n = 4g + r needs scale from lane 4g+r)
        float scr[4];
#pragma unroll
        for (int r = 0; r < 4; r++) scr[r] = __shfl(scale, 4 * g + r, 64);
#pragma unroll
        for (int es = 0; es < 7; es++)
#pragma unroll
            for (int r = 0; r < 4; r++) oacc[es][r] *= scr[r];

        // ---- P -> wave-private LDS (A-frag re-layout), swizzled ----
#pragma unroll
        for (int ls = 0; ls < 4; ls++)
            *(half4*)(pb + nl * 128 + ((32 * ls + 8 * g) ^ swp)) = ph[ls];

        // ---- PV: D[n][e] += mfma(A=P, B=V) ----
#pragma unroll
        for (int kl = 0; kl < 2; kl++) {
            half8 pf = *(const half8*)(pb + nl * 128 + ((64 * kl + 16 * g) ^ swp));
#pragma unroll
            for (int es = 0; es < 7; es++) {
                const int er = 16 * es + nl;
                half8 vf = *(const half8*)(vb + er * 128 + ((64 * kl + 16 * g) ^ ((er & 7) << 4)));
                oacc[es] = __builtin_amdgcn_mfma_f32_16x16x32_f16(pf, vf, oacc[es], 0, 0, 0);
            }
        }

        asm volatile("s_waitcnt vmcnt(0)" ::: "memory");
        __syncthreads();
    }

    // ---- epilogue ----
    const float inv = 1.0f / s_i;
    float invr[4];
#pragma unroll
    for (int r = 0; r < 4; r++) invr[r] = __shfl(inv, 4 * g + r, 64);
#pragma unroll
    for (int es = 0; es < 7; es++) {
        const int e = 16 * es + nl;
        if (e < Ee) {
#pragma unroll
            for (int r = 0; r < 4; r++) {
                const int n = n_base + 4 * g + r;
                if (n < Nn) out[((size_t)b * Nn + n) * Ee + e] = oacc[es][r] * invr[r];
            }
        }
    }
}

// ---------- fp32 fallback (verified R1 kernel) for ws too small ----------
constexpr int FNT = 16, FLT = 64, FLTP = 65;
__global__ __launch_bounds__(256)
void cwa_fwd(const float* __restrict__ x, const float* __restrict__ lf,
             float* __restrict__ out) {
    __shared__ float q[FNT][Ee];
    __shared__ float xts[Ee][FLTP];
    __shared__ float pl[FNT][FLT];
    const int tid = threadIdx.x, lane = tid & 63, w = tid >> 6;
    const int b = blockIdx.y, n0 = blockIdx.x * FNT;
    for (int idx = tid; idx < FNT * Ee; idx += 256) {
        int nl = idx / Ee, e = idx - nl * Ee;
        int n = n0 + nl;
        q[nl][e] = (n < Nn) ? lf[n * Ee + e] : 0.0f;
    }
    float m_i[4], s_i[4], a0[4], a1[4];
#pragma unroll
    for (int i = 0; i < 4; i++) { m_i[i] = -INFINITY; s_i[i] = 0.f; a0[i] = 0.f; a1[i] = 0.f; }
    const float* xb = x + (size_t)b * Ll * Ee;
    const bool hi_ok = lane < (Ee - 64);
    for (int l0 = 0; l0 < Ll; l0 += FLT) {
        const int nrows = min(FLT, Ll - l0);
        __syncthreads();
        for (int idx = tid; idx < FLT * (Ee / 4); idx += 256) {
            int r = idx / (Ee / 4), c4 = idx - r * (Ee / 4);
            float4 v = make_float4(0.f, 0.f, 0.f, 0.f);
            if (r < nrows) v = *reinterpret_cast<const float4*>(xb + (size_t)(l0 + r) * Ee + c4 * 4);
            xts[c4 * 4 + 0][r] = v.x; xts[c4 * 4 + 1][r] = v.y;
            xts[c4 * 4 + 2][r] = v.z; xts[c4 * 4 + 3][r] = v.w;
        }
        __syncthreads();
        float sc[4] = {0.f, 0.f, 0.f, 0.f};
        for (int e = 0; e < Ee; e++) {
            float xv = xts[e][lane];
#pragma unroll
            for (int i = 0; i < 4; i++) sc[i] = fmaf(q[4 * w + i][e], xv, sc[i]);
        }
        const bool valid = lane < nrows;
#pragma unroll
        for (int i = 0; i < 4; i++) {
            float s = valid ? sc[i] : -INFINITY;
            float tm = s;
#pragma unroll
            for (int msk = 32; msk >= 1; msk >>= 1) tm = fmaxf(tm, __shfl_xor(tm, msk, 64));
            float mn = fmaxf(m_i[i], tm);
            float p = __expf(s - mn);
            float sm = p;
#pragma unroll
            for (int msk = 32; msk >= 1; msk >>= 1) sm += __shfl_xor(sm, msk, 64);
            float scl = __expf(m_i[i] - mn);
            s_i[i] = s_i[i] * scl + sm; m_i[i] = mn;
            a0[i] *= scl; a1[i] *= scl;
            pl[4 * w + i][lane] = p;
        }
        __syncthreads();
#pragma unroll 4
        for (int l = 0; l < FLT; l++) {
            float xv0 = xts[lane][l];
            float xv1 = hi_ok ? xts[64 + lane][l] : 0.f;
#pragma unroll
            for (int i = 0; i < 4; i++) {
                float pv = pl[4 * w + i][l];
                a0[i] = fmaf(pv, xv0, a0[i]); a1[i] = fmaf(pv, xv1, a1[i]);
            }
        }
    }
#pragma unroll
    for (int i = 0; i < 4; i++) {
        int n = n0 + 4 * w + i;
        if (n >= Nn) continue;
        float inv = 1.0f / s_i[i];
        size_t base = ((size_t)b * Nn + n) * Ee;
        out[base + lane] = a0[i] * inv;
        if (hi_ok) out[base + 64 + lane] = a1[i] * inv;
    }
}

extern "C" void kernel_launch(void* const* d_in, const int* in_sizes, int n_in,
                              void* d_out, int out_size, void* d_ws, size_t ws_size,
                              hipStream_t stream) {
    const float* x  = (const float*)d_in[0];   // [8, 2500, 100]
    const float* lf = (const float*)d_in[1];   // [8922, 100]
    float* out = (float*)d_out;                // [8, 8922, 100]
    if (ws_size >= WS_NEED) {
        uint32_t* lf16 = (uint32_t*)d_ws;
        uint32_t* xww  = (uint32_t*)((char*)d_ws + OFF_XW);
        uint16_t* xtw  = (uint16_t*)((char*)d_ws + OFF_XT);
        prep_lf<<<NP * 64 / 256, 256, 0, stream>>>(lf, lf16);
        prep_xw<<<Bb * LP * 64 / 256, 256, 0, stream>>>(x, xww);
        prep_xt<<<dim3(LP / LT, Bb), 256, 0, stream>>>(x, xtw);
        cwa_mfma<<<dim3(NP / NTB, Bb), 512, 0, stream>>>(
            (const uint16_t*)d_ws, (const uint16_t*)((char*)d_ws + OFF_XW),
            (const uint16_t*)((char*)d_ws + OFF_XT), out);
    } else {
        dim3 grid((Nn + FNT - 1) / FNT, Bb);
        cwa_fwd<<<grid, dim3(256), 0, stream>>>(x, lf, out);
    }
}

// Round 4
// 248.284 us; speedup vs baseline: 11.7176x; 1.0882x over previous
//
#include <hip/hip_runtime.h>
#include <math.h>
#include <stdint.h>

typedef __attribute__((ext_vector_type(8))) _Float16 half8;
typedef __attribute__((ext_vector_type(4))) _Float16 half4;
typedef __attribute__((ext_vector_type(4))) float f32x4;

constexpr int Bb = 8, Ll = 2500, Ee = 100, Nn = 8922;
constexpr int LP = 2560, EP = 128, NP = 8960;   // padded dims
constexpr int LT = 64;                          // l-tile
constexpr int NTILES = LP / LT;                 // 40
constexpr int NTB = 128;                        // n per block (4 waves x 32)

constexpr size_t SZ_LF = (size_t)NP * EP * 2;
constexpr size_t SZ_XW = (size_t)Bb * LP * EP * 2;
constexpr size_t OFF_XW = SZ_LF;
constexpr size_t OFF_XT = OFF_XW + SZ_XW;
constexpr size_t WS_NEED = OFF_XT + SZ_XW;      // ~12.2 MB

__device__ __forceinline__ void gload16(const void* g, void* l) {
    __builtin_amdgcn_global_load_lds(
        (const __attribute__((address_space(1))) uint32_t*)g,
        (__attribute__((address_space(3))) uint32_t*)l, 16, 0, 0);
}

// ---------- prepass: lf -> f16 [NP][EP], bias col e=127 = 1.0 ----------
__global__ __launch_bounds__(256)
void prep_lf(const float* __restrict__ lf, uint32_t* __restrict__ dst) {
    int idx = blockIdx.x * 256 + threadIdx.x;   // n*64 + ep
    int n = idx >> 6, ep = idx & 63;
    int e0 = 2 * ep, e1 = e0 + 1;
    float f0 = (n < Nn && e0 < Ee) ? lf[(size_t)n * Ee + e0] : 0.f;
    float f1 = (n < Nn && e1 < Ee) ? lf[(size_t)n * Ee + e1] : (e1 == 127 ? 1.0f : 0.f);
    union { _Float16 h[2]; uint32_t u; } cv;
    cv.h[0] = (_Float16)f0; cv.h[1] = (_Float16)f1;
    dst[idx] = cv.u;
}

// ---------- fused prepass: x -> swizzled K rows [B][LP][EP] + swizzled V^T [B][EP][LP] ----------
__global__ __launch_bounds__(256)
void prep_x(const float* __restrict__ x, uint32_t* __restrict__ dxw,
            uint16_t* __restrict__ dxt) {
    __shared__ float lx[LT][101];               // +1 pad
    const int l0 = blockIdx.x * LT;
    const int b  = blockIdx.y;
    for (int i = threadIdx.x; i < LT * Ee; i += 256) {
        int ll = i / Ee, e = i - ll * Ee;
        int l = l0 + ll;
        lx[ll][e] = (l < Ll) ? x[((size_t)b * Ll + l) * Ee + e] : 0.f;
    }
    __syncthreads();
    // K rows: f16 pairs, 16B-block swizzle within 128B half-row; bias e=127
    for (int i = threadIdx.x; i < LT * 64; i += 256) {
        int row = i >> 6, ep = i & 63;
        int l = l0 + row;
        int e0 = 2 * ep, e1 = e0 + 1;
        float f0 = (e0 < Ee) ? lx[row][e0] : 0.f;
        float f1;
        if (e1 < Ee)        f1 = lx[row][e1];
        else if (e1 == 127) f1 = (l < Ll) ? 0.f : -20000.f;   // softmax mask bias
        else                f1 = 0.f;
        union { _Float16 h[2]; uint32_t u; } cv;
        cv.h[0] = (_Float16)f0; cv.h[1] = (_Float16)f1;
        int boff = (4 * ep) ^ ((row & 7) << 4);
        dxw[((size_t)b * LP + l) * 64 + (boff >> 2)] = cv.u;
    }
    // V^T rows: [e][l], 16B-block swizzle keyed by e
    for (int i = threadIdx.x; i < EP * LT; i += 256) {
        int e = i >> 6, ll = i & 63;
        float v = (e < Ee) ? lx[ll][e] : 0.f;
        uint32_t boff = (uint32_t)((2 * ll) ^ ((e & 7) << 4));
        union { _Float16 h; uint16_t u; } cv; cv.h = (_Float16)v;
        dxt[((size_t)b * EP + e) * LP + l0 + (boff >> 1)] = cv.u;
    }
}

// ---------- main: flash-style MFMA attention, 32 n per wave ----------
__global__ __launch_bounds__(256, 2)
void cwa_mfma(const uint16_t* __restrict__ lf16, const uint16_t* __restrict__ xw,
              const uint16_t* __restrict__ xt, float* __restrict__ out) {
    __shared__ __align__(128) char smem[2 * 32768 + 4 * 4096];   // 80 KB
    const int tid = threadIdx.x, lane = tid & 63, w = tid >> 6;  // w: 0..3
    const int g = lane >> 4, nl = lane & 15;
    const int b = blockIdx.y;
    const int n_base = blockIdx.x * NTB + w * 32;

    // Q fragments (B-operand): col n = nl (per 16-half), k = e = 32ks + 8g + j
    half8 qf[2][4];
#pragma unroll
    for (int nh = 0; nh < 2; nh++) {
        const uint16_t* qr = lf16 + (size_t)(n_base + 16 * nh + nl) * EP + 8 * g;
#pragma unroll
        for (int ks = 0; ks < 4; ks++) qf[nh][ks] = *(const half8*)(qr + 32 * ks);
    }

    f32x4 oacc[2][7];
#pragma unroll
    for (int nh = 0; nh < 2; nh++)
#pragma unroll
        for (int es = 0; es < 7; es++) oacc[nh][es] = f32x4{0.f, 0.f, 0.f, 0.f};
    float m_i[2] = {-INFINITY, -INFINITY}, s_i[2] = {0.f, 0.f};

    const char* xwb = (const char*)(xw + (size_t)b * LP * EP);
    const char* xtb = (const char*)(xt + (size_t)b * EP * LP);

    auto stage = [&](int t, char* kbuf) {
        const char* kg = xwb + (size_t)t * LT * EP * 2;
        const char* vg = xtb + (size_t)t * LT * 2;
        char* vbuf = kbuf + 16384;
#pragma unroll
        for (int i = 0; i < 4; i++) {
            int uo = i * 4096 + w * 1024;
            gload16(kg + uo + lane * 16, kbuf + uo);
        }
#pragma unroll
        for (int i = 0; i < 4; i++) {
            int e0 = w * 32 + i * 8;
            gload16(vg + (size_t)(e0 + (lane >> 3)) * (LP * 2) + (lane & 7) * 16,
                    vbuf + e0 * 128);
        }
    };

    stage(0, smem);
    asm volatile("s_waitcnt vmcnt(0)" ::: "memory");
    __syncthreads();

    char* pb = smem + 65536 + w * 4096;     // wave-private P buffer, 32 rows x 128B
    const int swp = (nl & 7) << 4;

    for (int t = 0; t < NTILES; t++) {
        const int buf = t & 1;
        const char* kb = smem + buf * 32768;
        const char* vb = kb + 16384;

        if (t + 1 < NTILES) stage(t + 1, smem + (buf ^ 1) * 32768);

        // ---- QK^T: S^T[l][n] = mfma(A=K, B=Q), each kf feeds both n-halves ----
        f32x4 sacc[2][4];
#pragma unroll
        for (int nh = 0; nh < 2; nh++)
#pragma unroll
            for (int ls = 0; ls < 4; ls++) sacc[nh][ls] = f32x4{0.f, 0.f, 0.f, 0.f};
#pragma unroll
        for (int ls = 0; ls < 4; ls++) {
            const int lrow = 16 * ls + nl;
            const char* kr = kb + lrow * 256;
            const int sw = (lrow & 7) << 4;
#pragma unroll
            for (int ks = 0; ks < 4; ks++) {
                half8 kf = *(const half8*)(kr + ((64 * ks + 16 * g) ^ sw));
                sacc[0][ls] = __builtin_amdgcn_mfma_f32_16x16x32_f16(kf, qf[0][ks], sacc[0][ls], 0, 0, 0);
                sacc[1][ls] = __builtin_amdgcn_mfma_f32_16x16x32_f16(kf, qf[1][ks], sacc[1][ls], 0, 0, 0);
            }
        }

        // ---- online softmax over l (lane's 16 values share col n = nl per half) ----
        float scale_s[2];
        half4 ph[2][4];
#pragma unroll
        for (int nh = 0; nh < 2; nh++) {
            float tm = -INFINITY;
#pragma unroll
            for (int ls = 0; ls < 4; ls++)
#pragma unroll
                for (int r = 0; r < 4; r++) tm = fmaxf(tm, sacc[nh][ls][r]);
            tm = fmaxf(tm, __shfl_xor(tm, 16, 64));
            tm = fmaxf(tm, __shfl_xor(tm, 32, 64));
            const float mn = fmaxf(m_i[nh], tm);
            scale_s[nh] = __expf(m_i[nh] - mn);
            float ts = 0.f;
#pragma unroll
            for (int ls = 0; ls < 4; ls++)
#pragma unroll
                for (int r = 0; r < 4; r++) {
                    float pv = __expf(sacc[nh][ls][r] - mn);
                    ts += pv;
                    ph[nh][ls][r] = (_Float16)pv;
                }
            ts += __shfl_xor(ts, 16, 64);
            ts += __shfl_xor(ts, 32, 64);
            s_i[nh] = s_i[nh] * scale_s[nh] + ts;
            m_i[nh] = mn;
        }

        // rescale output acc (row n = 4g + r gets scale from lane with nl = 4g+r)
#pragma unroll
        for (int nh = 0; nh < 2; nh++)
#pragma unroll
            for (int r = 0; r < 4; r++) {
                float scr = __shfl(scale_s[nh], 4 * g + r, 64);
#pragma unroll
                for (int es = 0; es < 7; es++) oacc[nh][es][r] *= scr;
            }

        // ---- P -> wave-private LDS (A-frag re-layout), swizzled ----
#pragma unroll
        for (int nh = 0; nh < 2; nh++)
#pragma unroll
            for (int ls = 0; ls < 4; ls++)
                *(half4*)(pb + (16 * nh + nl) * 128 + ((32 * ls + 8 * g) ^ swp)) = ph[nh][ls];

        // ---- PV: D[n][e] += mfma(A=P, B=V), each vf feeds both n-halves ----
#pragma unroll
        for (int kl = 0; kl < 2; kl++) {
            half8 pf0 = *(const half8*)(pb + nl * 128 + ((64 * kl + 16 * g) ^ swp));
            half8 pf1 = *(const half8*)(pb + (16 + nl) * 128 + ((64 * kl + 16 * g) ^ swp));
#pragma unroll
            for (int es = 0; es < 7; es++) {
                const int er = 16 * es + nl;
                half8 vf = *(const half8*)(vb + er * 128 + ((64 * kl + 16 * g) ^ ((er & 7) << 4)));
                oacc[0][es] = __builtin_amdgcn_mfma_f32_16x16x32_f16(pf0, vf, oacc[0][es], 0, 0, 0);
                oacc[1][es] = __builtin_amdgcn_mfma_f32_16x16x32_f16(pf1, vf, oacc[1][es], 0, 0, 0);
            }
        }

        asm volatile("s_waitcnt vmcnt(0)" ::: "memory");
        __syncthreads();
    }

    // ---- epilogue ----
#pragma unroll
    for (int nh = 0; nh < 2; nh++) {
        const float inv = 1.0f / s_i[nh];
#pragma unroll
        for (int r = 0; r < 4; r++) {
            const float invr = __shfl(inv, 4 * g + r, 64);
            const int n = n_base + 16 * nh + 4 * g + r;
            if (n < Nn) {
#pragma unroll
                for (int es = 0; es < 7; es++) {
                    const int e = 16 * es + nl;
                    if (e < Ee) out[((size_t)b * Nn + n) * Ee + e] = oacc[nh][es][r] * invr;
                }
            }
        }
    }
}

// ---------- fp32 fallback (verified R1 kernel) for ws too small ----------
constexpr int FNT = 16, FLT = 64, FLTP = 65;
__global__ __launch_bounds__(256)
void cwa_fwd(const float* __restrict__ x, const float* __restrict__ lf,
             float* __restrict__ out) {
    __shared__ float q[FNT][Ee];
    __shared__ float xts[Ee][FLTP];
    __shared__ float pl[FNT][FLT];
    const int tid = threadIdx.x, lane = tid & 63, w = tid >> 6;
    const int b = blockIdx.y, n0 = blockIdx.x * FNT;
    for (int idx = tid; idx < FNT * Ee; idx += 256) {
        int nl = idx / Ee, e = idx - nl * Ee;
        int n = n0 + nl;
        q[nl][e] = (n < Nn) ? lf[n * Ee + e] : 0.0f;
    }
    float m_i[4], s_i[4], a0[4], a1[4];
#pragma unroll
    for (int i = 0; i < 4; i++) { m_i[i] = -INFINITY; s_i[i] = 0.f; a0[i] = 0.f; a1[i] = 0.f; }
    const float* xb = x + (size_t)b * Ll * Ee;
    const bool hi_ok = lane < (Ee - 64);
    for (int l0 = 0; l0 < Ll; l0 += FLT) {
        const int nrows = min(FLT, Ll - l0);
        __syncthreads();
        for (int idx = tid; idx < FLT * (Ee / 4); idx += 256) {
            int r = idx / (Ee / 4), c4 = idx - r * (Ee / 4);
            float4 v = make_float4(0.f, 0.f, 0.f, 0.f);
            if (r < nrows) v = *reinterpret_cast<const float4*>(xb + (size_t)(l0 + r) * Ee + c4 * 4);
            xts[c4 * 4 + 0][r] = v.x; xts[c4 * 4 + 1][r] = v.y;
            xts[c4 * 4 + 2][r] = v.z; xts[c4 * 4 + 3][r] = v.w;
        }
        __syncthreads();
        float sc[4] = {0.f, 0.f, 0.f, 0.f};
        for (int e = 0; e < Ee; e++) {
            float xv = xts[e][lane];
#pragma unroll
            for (int i = 0; i < 4; i++) sc[i] = fmaf(q[4 * w + i][e], xv, sc[i]);
        }
        const bool valid = lane < nrows;
#pragma unroll
        for (int i = 0; i < 4; i++) {
            float s = valid ? sc[i] : -INFINITY;
            float tm = s;
#pragma unroll
            for (int msk = 32; msk >= 1; msk >>= 1) tm = fmaxf(tm, __shfl_xor(tm, msk, 64));
            float mn = fmaxf(m_i[i], tm);
            float p = __expf(s - mn);
            float sm = p;
#pragma unroll
            for (int msk = 32; msk >= 1; msk >>= 1) sm += __shfl_xor(sm, msk, 64);
            float scl = __expf(m_i[i] - mn);
            s_i[i] = s_i[i] * scl + sm; m_i[i] = mn;
            a0[i] *= scl; a1[i] *= scl;
            pl[4 * w + i][lane] = p;
        }
        __syncthreads();
#pragma unroll 4
        for (int l = 0; l < FLT; l++) {
            float xv0 = xts[lane][l];
            float xv1 = hi_ok ? xts[64 + lane][l] : 0.f;
#pragma unroll
            for (int i = 0; i < 4; i++) {
                float pv = pl[4 * w + i][l];
                a0[i] = fmaf(pv, xv0, a0[i]); a1[i] = fmaf(pv, xv1, a1[i]);
            }
        }
    }
#pragma unroll
    for (int i = 0; i < 4; i++) {
        int n = n0 + 4 * w + i;
        if (n >= Nn) continue;
        float inv = 1.0f / s_i[i];
        size_t base = ((size_t)b * Nn + n) * Ee;
        out[base + lane] = a0[i] * inv;
        if (hi_ok) out[base + 64 + lane] = a1[i] * inv;
    }
}

extern "C" void kernel_launch(void* const* d_in, const int* in_sizes, int n_in,
                              void* d_out, int out_size, void* d_ws, size_t ws_size,
                              hipStream_t stream) {
    const float* x  = (const float*)d_in[0];   // [8, 2500, 100]
    const float* lf = (const float*)d_in[1];   // [8922, 100]
    float* out = (float*)d_out;                // [8, 8922, 100]
    if (ws_size >= WS_NEED) {
        prep_lf<<<NP * 64 / 256, 256, 0, stream>>>(lf, (uint32_t*)d_ws);
        prep_x<<<dim3(LP / LT, Bb), 256, 0, stream>>>(
            x, (uint32_t*)((char*)d_ws + OFF_XW), (uint16_t*)((char*)d_ws + OFF_XT));
        cwa_mfma<<<dim3(NP / NTB, Bb), 256, 0, stream>>>(
            (const uint16_t*)d_ws, (const uint16_t*)((char*)d_ws + OFF_XW),
            (const uint16_t*)((char*)d_ws + OFF_XT), out);
    } else {
        dim3 grid((Nn + FNT - 1) / FNT, Bb);
        cwa_fwd<<<grid, dim3(256), 0, stream>>>(x, lf, out);
    }
}